// Round 2
// baseline (812.806 us; speedup 1.0000x reference)
//
#include <hip/hip_runtime.h>

typedef short s8v __attribute__((ext_vector_type(8)));
typedef float f4v __attribute__((ext_vector_type(4)));

__device__ __forceinline__ unsigned short f2bf(float x) {
  union { float f; unsigned u; } v; v.f = x;
  unsigned r = v.u + 0x7fffu + ((v.u >> 16) & 1u);
  return (unsigned short)(r >> 16);
}
__device__ __forceinline__ float bf2f(unsigned u16) {
  union { unsigned u; float f; } v; v.u = u16 << 16;
  return v.f;
}
__device__ __forceinline__ s8v as_s8(int4 v) { union { int4 i; s8v s; } u; u.i = v; return u.s; }
__device__ __forceinline__ f4v as_f4(int4 v) { union { int4 i; f4v f; } u; u.i = v; return u.f; }
__device__ __forceinline__ int4 as_i4(f4v v) { union { f4v f; int4 i; } u; u.f = v; return u.i; }

// ---------------- prep: bf16 casts + weight reorg + accum zero ----------------
__global__ __launch_bounds__(256) void prep_kernel(
    const float* __restrict__ q, const float* __restrict__ k,
    const float* __restrict__ w1, const float* __restrict__ w2, const float* __restrict__ w3,
    unsigned short* __restrict__ Qb, unsigned short* __restrict__ Kb,
    unsigned short* __restrict__ W1, unsigned short* __restrict__ W2,
    unsigned short* __restrict__ W3, float* __restrict__ accum) {
  int idx = blockIdx.x * 256 + threadIdx.x;
  const int NQ = 2048 * 512;
  if (idx < NQ) { Qb[idx] = f2bf(q[idx]); return; }
  idx -= NQ;
  if (idx < NQ) { Kb[idx] = f2bf(k[idx]); return; }
  idx -= NQ;
  if (idx < 5120) {                      // W1 [5 dy][32 m][32 k], k = dx*2 + c
    int dy = idx >> 10, r = idx & 1023, m = r >> 5, kk = r & 31;
    float v = 0.f;
    if (m < 30 && kk < 10) v = w1[m * 50 + (kk & 1) * 25 + dy * 5 + (kk >> 1)];
    W1[idx] = f2bf(v); return;
  }
  idx -= 5120;
  if (idx < 25600) {                     // W2 [5 dy][32 m][160 kk], kk = dx*32 + c
    int dy = idx / 5120, r = idx - dy * 5120, m = r / 160, kk = r - m * 160;
    int c = kk & 31, dx = kk >> 5;
    float v = 0.f;
    if (m < 30 && c < 30) v = w2[m * 750 + c * 25 + dy * 5 + dx];
    W2[idx] = f2bf(v); return;
  }
  idx -= 25600;
  if (idx < 288) {                       // W3 [9 dd=dy*3+dx][32 c]
    int dd = idx >> 5, c = idx & 31;
    float v = (c < 30) ? w3[c * 9 + dd] : 0.f;
    W3[idx] = f2bf(v); return;
  }
  idx -= 288;
  if (idx == 0) *accum = 0.f;
}

// ---------------- row norms ----------------
__global__ __launch_bounds__(256) void norms_kernel(
    const float* __restrict__ q, const float* __restrict__ k,
    float* __restrict__ nq, float* __restrict__ nk) {
  int wv = threadIdx.x >> 6, l = threadIdx.x & 63;
  int row = blockIdx.x * 4 + wv;
  const float* src = (row < 2048) ? (q + row * 512) : (k + (row - 2048) * 512);
  float s = 0.f;
  for (int i = l; i < 512; i += 64) { float v = src[i]; s += v * v; }
  for (int off = 32; off; off >>= 1) s += __shfl_xor(s, off);
  if (l == 0) { if (row < 2048) nq[row] = s; else nk[row - 2048] = s; }
}

// ---------------- D = cdist GEMM (bf16 MFMA cross-term, fp32 norms) ----------------
__global__ __launch_bounds__(256) void dgemm_kernel(
    const unsigned short* __restrict__ Qb, const unsigned short* __restrict__ Kb,
    const float* __restrict__ nq, const float* __restrict__ nk,
    float* __restrict__ Dout) {
  __shared__ int4 sm[2 * 128 * 9];
  const int t = threadIdx.x;
  const int bm = blockIdx.x, bn = blockIdx.y;
  const int wv = t >> 6, l = t & 63;
  const int m0 = (wv & 1) * 64, n0 = (wv >> 1) * 64;
  const int l15 = l & 15, q4 = l >> 4;
  f4v acc[4][4] = {};
  const int4* Qg = (const int4*)Qb;
  const int4* Kg = (const int4*)Kb;
  for (int kt = 0; kt < 8; ++kt) {
    __syncthreads();
#pragma unroll
    for (int i = 0; i < 4; ++i) {
      int c = t + i * 256;
      int row = c >> 3, kq = c & 7;
      sm[row * 9 + kq]        = Qg[(bm * 128 + row) * 64 + kt * 8 + kq];
      sm[1152 + row * 9 + kq] = Kg[(bn * 128 + row) * 64 + kt * 8 + kq];
    }
    __syncthreads();
#pragma unroll
    for (int s = 0; s < 2; ++s) {
      s8v af[4], bfr[4];
#pragma unroll
      for (int mt = 0; mt < 4; ++mt)
        af[mt] = as_s8(sm[(m0 + mt * 16 + l15) * 9 + s * 4 + q4]);
#pragma unroll
      for (int nt = 0; nt < 4; ++nt)
        bfr[nt] = as_s8(sm[1152 + (n0 + nt * 16 + l15) * 9 + s * 4 + q4]);
#pragma unroll
      for (int mt = 0; mt < 4; ++mt)
#pragma unroll
        for (int nt = 0; nt < 4; ++nt)
          acc[mt][nt] = __builtin_amdgcn_mfma_f32_16x16x32_bf16(af[mt], bfr[nt], acc[mt][nt], 0, 0, 0);
    }
  }
  float nkv[4];
#pragma unroll
  for (int nt = 0; nt < 4; ++nt) nkv[nt] = nk[bn * 128 + n0 + nt * 16 + l15];
#pragma unroll
  for (int mt = 0; mt < 4; ++mt)
#pragma unroll
    for (int reg = 0; reg < 4; ++reg) {
      int gr = bm * 128 + m0 + mt * 16 + q4 * 4 + reg;
      float nqv = nq[gr];
#pragma unroll
      for (int nt = 0; nt < 4; ++nt) {
        int gc = bn * 128 + n0 + nt * 16 + l15;
        float d2 = nqv + nkv[nt] - 2.f * acc[mt][nt][reg];
        Dout[gr * 2048 + gc] = sqrtf(fmaxf(d2, 0.f));
      }
    }
}

// ---------------- fused conv1+conv2+conv3+residual, row-pipelined ----------------
// Tile: 62 out-px wide, 32 out rows. 12 waves: w0-7 conv2, w8-9 conv1, w10-11 conv3+DP-stage.
// Rings (LDS): DP 2x96 u32 ; act1 2x80px x 32ch bf16 ; act2 2x68px x 32ch x (hi,lo) bf16.
__global__ __launch_bounds__(768, 3) void fused_conv(
    const float* __restrict__ Dmat, const float* __restrict__ lq, const float* __restrict__ lk,
    const unsigned short* __restrict__ W1g, const unsigned short* __restrict__ W2g,
    const unsigned short* __restrict__ W3g,
    const float* __restrict__ b1, const float* __restrict__ b2, const float* __restrict__ b3,
    float* __restrict__ Sout) {
  __shared__ int4 a1s[640];       // [2][80][4]
  __shared__ int4 a2s[1088];      // [2][68][8]  (int4 0-3 = hi ch-groups, 4-7 = lo)
  __shared__ unsigned dps[192];   // [2][96]
  const int t = threadIdx.x;
  const int wv = t >> 6, l = t & 63, l15 = l & 15, q4 = l >> 4;
  const int x0 = blockIdx.x * 62, y0 = blockIdx.y * 32;

  int4 uni[25];     // conv2: A2[dy][s] ; conv1: acc ring [T][5] ; conv3: acc ring [tt][3]
  int4 uni2[9];     // conv2: acc ring[5] ; conv1: A1[dy] ; conv3: A3[dy*3+s]
  float bias4[4];
  const int cls = (wv < 8) ? 0 : (wv < 10 ? 1 : 2);
  const int mb = (cls == 0) ? (wv >> 2) : (wv & 1);
  const int T2 = wv & 3;

  if (cls == 0) {
    const int4* W2i = (const int4*)W2g;
#pragma unroll
    for (int d = 0; d < 5; ++d)
#pragma unroll
      for (int s = 0; s < 5; ++s)
        uni[d * 5 + s] = W2i[(d * 32 + mb * 16 + l15) * 20 + s * 4 + q4];
#pragma unroll
    for (int j = 0; j < 5; ++j) uni2[j] = make_int4(0, 0, 0, 0);
#pragma unroll
    for (int i = 0; i < 4; ++i) {
      int ch = mb * 16 + q4 * 4 + i;
      bias4[i] = (ch < 30) ? b2[ch] : 0.f;
    }
  } else if (cls == 1) {
    const int4* W1i = (const int4*)W1g;
#pragma unroll
    for (int d = 0; d < 5; ++d) uni2[d] = W1i[(d * 32 + mb * 16 + l15) * 4 + q4];
#pragma unroll
    for (int j = 0; j < 25; ++j) uni[j] = make_int4(0, 0, 0, 0);
#pragma unroll
    for (int i = 0; i < 4; ++i) {
      int ch = mb * 16 + q4 * 4 + i;
      bias4[i] = (ch < 30) ? b1[ch] : 0.f;
    }
  } else {
    const int4* W3i = (const int4*)W3g;
#pragma unroll
    for (int j = 0; j < 9; ++j)
      uni2[j] = (l15 == 0) ? W3i[j * 4 + q4] : make_int4(0, 0, 0, 0);
#pragma unroll
    for (int j = 0; j < 6; ++j) uni[j] = make_int4(0, 0, 0, 0);
    bias4[0] = b3[0];
  }
  if (t < 64) {  // zero act2 pad px 64..67 (read by masked lanes only)
    int sl = t >> 5, rem = t & 31;
    a2s[(sl * 68 + 64 + (rem >> 3)) * 8 + (rem & 7)] = make_int4(0, 0, 0, 0);
  }
  if (t < 96) {  // prefill DP row y0-5
    int rs = y0 - 5, px = t, gx = x0 - 5 + px;
    unsigned v = 0u;
    if (rs >= 0 && gx >= 0 && gx < 2048) {
      float Dv = Dmat[rs * 2048 + gx];
      float Pv = fabsf(lq[rs] - lk[gx]);
      v = (unsigned)f2bf(Dv) | ((unsigned)f2bf(Pv) << 16);
    }
    dps[(rs & 1) * 96 + px] = v;
  }
  __syncthreads();

  for (int r = y0 - 7; r <= y0 + 36; ++r) {
    if (cls == 0) {
      // ---- conv2: consume act1 row rc = r-1 into 5 sliding row-accs ----
      int rc = r - 1;
      if (rc >= y0 - 3 && rc <= y0 + 34) {
        int sl = rc & 1;
#pragma unroll
        for (int s = 0; s < 5; ++s) {
          int px = T2 * 16 + l15 + s;
          s8v B = as_s8(a1s[(sl * 80 + px) * 4 + q4]);
#pragma unroll
          for (int d = 0; d < 5; ++d)
            uni2[4 - d] = as_i4(__builtin_amdgcn_mfma_f32_16x16x32_bf16(
                as_s8(uni[d * 5 + s]), B, as_f4(uni2[4 - d]), 0, 0, 0));
        }
      }
      int r2c = r - 3;  // completed act2 row
      if (r2c >= y0 - 1 && r2c <= y0 + 32) {
        int px2 = T2 * 16 + l15;
        int gx2 = x0 - 1 + px2;
        bool ok = (r2c >= 0 && r2c < 2048 && gx2 >= 0 && gx2 < 2048);
        f4v a = as_f4(uni2[0]);
        unsigned short* dst = (unsigned short*)a2s + ((r2c & 1) * 68 + px2) * 64;
        ushort4 hv, lv;
        {
          float v0 = ok ? fmaxf(a[0] + bias4[0], 0.f) : 0.f;
          float v1 = ok ? fmaxf(a[1] + bias4[1], 0.f) : 0.f;
          float v2 = ok ? fmaxf(a[2] + bias4[2], 0.f) : 0.f;
          float v3 = ok ? fmaxf(a[3] + bias4[3], 0.f) : 0.f;
          hv.x = f2bf(v0); hv.y = f2bf(v1); hv.z = f2bf(v2); hv.w = f2bf(v3);
          lv.x = f2bf(v0 - bf2f(hv.x)); lv.y = f2bf(v1 - bf2f(hv.y));
          lv.z = f2bf(v2 - bf2f(hv.z)); lv.w = f2bf(v3 - bf2f(hv.w));
        }
        *(ushort4*)(dst + mb * 16 + q4 * 4) = hv;
        *(ushort4*)(dst + 32 + mb * 16 + q4 * 4) = lv;
      }
#pragma unroll
      for (int j = 0; j < 4; ++j) uni2[j] = uni2[j + 1];
      uni2[4] = make_int4(0, 0, 0, 0);
    } else if (cls == 1) {
      // ---- conv1: consume DP row rd = r+2 into 5 tiles x 5 sliding row-accs ----
      if (r <= y0 + 34) {
        int sl = (r + 2) & 1;
#pragma unroll
        for (int T1 = 0; T1 < 5; ++T1) {
          int pb = sl * 96 + T1 * 16 + l15 + q4 * 4;
          int4 bi;
          bi.x = (int)dps[pb + 0]; bi.y = (int)dps[pb + 1];
          bi.z = (int)dps[pb + 2]; bi.w = (int)dps[pb + 3];
          s8v B = as_s8(bi);
#pragma unroll
          for (int d = 0; d < 5; ++d)
            uni[T1 * 5 + (4 - d)] = as_i4(__builtin_amdgcn_mfma_f32_16x16x32_bf16(
                as_s8(uni2[d]), B, as_f4(uni[T1 * 5 + (4 - d)]), 0, 0, 0));
        }
        if (r >= y0 - 3) {  // completed act1 row r
          bool rowok = (r >= 0 && r < 2048);
#pragma unroll
          for (int T1 = 0; T1 < 5; ++T1) {
            int px = T1 * 16 + l15;
            int gx = x0 - 3 + px;
            bool ok = rowok && gx >= 0 && gx < 2048;
            f4v a = as_f4(uni[T1 * 5]);
            ushort4 sv;
            sv.x = f2bf(ok ? fmaxf(a[0] + bias4[0], 0.f) : 0.f);
            sv.y = f2bf(ok ? fmaxf(a[1] + bias4[1], 0.f) : 0.f);
            sv.z = f2bf(ok ? fmaxf(a[2] + bias4[2], 0.f) : 0.f);
            sv.w = f2bf(ok ? fmaxf(a[3] + bias4[3], 0.f) : 0.f);
            *(ushort4*)((unsigned short*)a1s + ((r & 1) * 80 + px) * 32 + mb * 16 + q4 * 4) = sv;
          }
        }
#pragma unroll
        for (int T1 = 0; T1 < 5; ++T1) {
#pragma unroll
          for (int j = 0; j < 4; ++j) uni[T1 * 5 + j] = uni[T1 * 5 + j + 1];
          uni[T1 * 5 + 4] = make_int4(0, 0, 0, 0);
        }
      }
    } else {
      // ---- DP staging loads (issue early) ----
      int rs = r + 3;
      bool stact = (rs >= y0 - 4 && rs <= y0 + 36);
      int spx = (wv == 10) ? l : (64 + l);
      bool lact = stact && (spx < 96);
      int sgx = x0 - 5 + spx;
      unsigned pv = 0u;
      if (lact && rs >= 0 && rs < 2048 && sgx >= 0 && sgx < 2048) {
        float Dv = Dmat[rs * 2048 + sgx];
        float Pv = fabsf(lq[rs] - lk[sgx]);
        pv = (unsigned)f2bf(Dv) | ((unsigned)f2bf(Pv) << 16);
      }
      // ---- conv3: consume act2 row ra = r-4 (hi+lo) into 3 sliding row-accs ----
      int ra = r - 4;
      int T3 = (wv - 10) * 2;
      if (ra >= y0 - 1 && ra <= y0 + 32) {
        int sl = ra & 1;
#pragma unroll
        for (int tt = 0; tt < 2; ++tt) {
#pragma unroll
          for (int s = 0; s < 3; ++s) {
            int px = (T3 + tt) * 16 + l15 + s;
            s8v Bh = as_s8(a2s[(sl * 68 + px) * 8 + q4]);
            s8v Bl = as_s8(a2s[(sl * 68 + px) * 8 + 4 + q4]);
#pragma unroll
            for (int d = 0; d < 3; ++d) {
              f4v acc = as_f4(uni[tt * 3 + (2 - d)]);
              acc = __builtin_amdgcn_mfma_f32_16x16x32_bf16(as_s8(uni2[d * 3 + s]), Bh, acc, 0, 0, 0);
              acc = __builtin_amdgcn_mfma_f32_16x16x32_bf16(as_s8(uni2[d * 3 + s]), Bl, acc, 0, 0, 0);
              uni[tt * 3 + (2 - d)] = as_i4(acc);
            }
          }
        }
      }
      int y = r - 5;  // completed output row
      if (y >= y0 && y <= y0 + 31) {
#pragma unroll
        for (int tt = 0; tt < 2; ++tt) {
          int ox = (T3 + tt) * 16 + l15;
          int gx = x0 + ox;
          if (q4 == 0 && ox < 62 && gx < 2048) {
            Sout[y * 2048 + gx] = as_f4(uni[tt * 3])[0] + bias4[0] + Dmat[y * 2048 + gx];
          }
        }
      }
#pragma unroll
      for (int tt = 0; tt < 2; ++tt) {
        uni[tt * 3 + 0] = uni[tt * 3 + 1];
        uni[tt * 3 + 1] = uni[tt * 3 + 2];
        uni[tt * 3 + 2] = make_int4(0, 0, 0, 0);
      }
      if (lact) dps[(rs & 1) * 96 + spx] = pv;
    }
    __syncthreads();
  }
}

// ---------------- row softmax (in-place on d_out) + dis accumulation ----------------
__global__ __launch_bounds__(256) void softmax_kernel(
    float* __restrict__ S, const float* __restrict__ Dmat, float* __restrict__ accum) {
  const int row = blockIdx.x, t = threadIdx.x;
  float* Srow = S + row * 2048;
  const float* Drow = Dmat + row * 2048;
  float sv[8], dv[8];
  float mx = -1e30f;
#pragma unroll
  for (int i = 0; i < 8; ++i) {
    sv[i] = -Srow[t + i * 256];
    dv[i] = Drow[t + i * 256];
    mx = fmaxf(mx, sv[i]);
  }
  __shared__ float red[4], redz[4], redw[4];
  for (int off = 32; off; off >>= 1) mx = fmaxf(mx, __shfl_xor(mx, off));
  const int wv = t >> 6, l = t & 63;
  if (l == 0) red[wv] = mx;
  __syncthreads();
  mx = fmaxf(fmaxf(red[0], red[1]), fmaxf(red[2], red[3]));
  float z = 0.f, w = 0.f, ev[8];
#pragma unroll
  for (int i = 0; i < 8; ++i) {
    ev[i] = __expf(sv[i] - mx);
    z += ev[i];
    w += ev[i] * dv[i];
  }
  for (int off = 32; off; off >>= 1) { z += __shfl_xor(z, off); w += __shfl_xor(w, off); }
  if (l == 0) { redz[wv] = z; redw[wv] = w; }
  __syncthreads();
  z = redz[0] + redz[1] + redz[2] + redz[3];
  w = redw[0] + redw[1] + redw[2] + redw[3];
  float inv = 1.f / z;
#pragma unroll
  for (int i = 0; i < 8; ++i) Srow[t + i * 256] = ev[i] * inv;
  if (t == 0) atomicAdd(accum, w * inv);
}

__global__ void finalize_kernel(const float* __restrict__ accum, float* __restrict__ out) {
  if (threadIdx.x == 0) out[0] = accum[0] * (1.f / 2048.f);
}

// ---------------- host ----------------
extern "C" void kernel_launch(void* const* d_in, const int* in_sizes, int n_in,
                              void* d_out, int out_size, void* d_ws, size_t ws_size,
                              hipStream_t stream) {
  const float* seq_q = (const float*)d_in[0];
  const float* seq_k = (const float*)d_in[1];
  const float* len_q = (const float*)d_in[2];
  const float* len_k = (const float*)d_in[3];
  const float* w1 = (const float*)d_in[4];
  const float* b1 = (const float*)d_in[5];
  const float* w2 = (const float*)d_in[6];
  const float* b2 = (const float*)d_in[7];
  const float* w3 = (const float*)d_in[8];
  const float* b3 = (const float*)d_in[9];

  char* ws = (char*)d_ws;
  unsigned short* Qb  = (unsigned short*)(ws);                         // 2 MiB
  unsigned short* Kb  = (unsigned short*)(ws + ((size_t)2 << 20));     // 2 MiB
  float* nq           = (float*)(ws + ((size_t)4 << 20));              // 8 KiB
  float* nk           = (float*)(ws + ((size_t)4 << 20) + 16384);
  unsigned short* W1  = (unsigned short*)(ws + ((size_t)4 << 20) + 32768);   // 10 KiB
  unsigned short* W2  = (unsigned short*)(ws + ((size_t)4 << 20) + 65536);   // 50 KiB
  unsigned short* W3  = (unsigned short*)(ws + ((size_t)4 << 20) + 131072);  // 576 B
  float* accum        = (float*)(ws + ((size_t)4 << 20) + 163840);
  float* Dmat         = (float*)(ws + ((size_t)5 << 20));              // 16 MiB
  float* out = (float*)d_out;

  const int prep_total = 2 * 2048 * 512 + 5120 + 25600 + 288 + 1;
  prep_kernel<<<(prep_total + 255) / 256, 256, 0, stream>>>(
      seq_q, seq_k, w1, w2, w3, Qb, Kb, W1, W2, W3, accum);
  norms_kernel<<<1024, 256, 0, stream>>>(seq_q, seq_k, nq, nk);
  dgemm_kernel<<<dim3(16, 16), 256, 0, stream>>>(Qb, Kb, nq, nk, Dmat);
  fused_conv<<<dim3(34, 64), 768, 0, stream>>>(
      Dmat, len_q, len_k, W1, W2, W3, b1, b2, b3, out);
  softmax_kernel<<<2048, 256, 0, stream>>>(out, Dmat, accum);
  finalize_kernel<<<1, 64, 0, stream>>>(accum, out + 4194304);
}